// Round 19
// baseline (225.245 us; speedup 1.0000x reference)
//
#include <hip/hip_runtime.h>
#include <stdint.h>

#define SEQ 2048
#define MROWS 8192
#define LOG2E 1.44269504f

typedef __attribute__((ext_vector_type(8))) _Float16 f16x8;
typedef __attribute__((ext_vector_type(2))) __fp16 fp16x2_t;   // cvt_pkrtz return type
typedef __attribute__((ext_vector_type(8))) unsigned short ushort8;
typedef __attribute__((ext_vector_type(4))) unsigned short ushort4_t;
typedef __attribute__((ext_vector_type(4))) float f32x4;
typedef __attribute__((ext_vector_type(16))) float f32x16;

__device__ __forceinline__ unsigned short f32_to_f16u(float f) {
  union { _Float16 h; unsigned short u; } v; v.h = (_Float16)f; return v.u;
}

__device__ __forceinline__ unsigned int pk_u32(float a, float b) {
  union { fp16x2_t h; unsigned int u; } v;
  v.h = __builtin_amdgcn_cvt_pkrtz(a, b);
  return v.u;
}

__device__ __forceinline__ ushort8 pack8_rtz(float4 f0, float4 f1) {
  union { fp16x2_t h2[4]; ushort8 u8; } pk;
  pk.h2[0] = __builtin_amdgcn_cvt_pkrtz(f0.x, f0.y);
  pk.h2[1] = __builtin_amdgcn_cvt_pkrtz(f0.z, f0.w);
  pk.h2[2] = __builtin_amdgcn_cvt_pkrtz(f1.x, f1.y);
  pk.h2[3] = __builtin_amdgcn_cvt_pkrtz(f1.z, f1.w);
  return pk.u8;
}

// async global(16B/lane) -> LDS (wave-uniform base + lane*16)
__device__ __forceinline__ void gload16(const void* g, void* l) {
  __builtin_amdgcn_global_load_lds(
      (const __attribute__((address_space(1))) unsigned int*)g,
      (__attribute__((address_space(3))) unsigned int*)l, 16, 0, 0);
}

// softmax: max-tree vote defer-max, tree-summed rsl; exp2 overwrites s with P;
// pack P for the 32x32 PV B-operand via cvt_pk + permlane32_swap.
__device__ __forceinline__ void softmax32(f32x16* s, f32x16* o,
                                          float& mrun, float& lrun, f16x8* pf) {
  float m01 = fmaxf(fmaxf(s[0][0], s[0][1]), fmaxf(s[0][2], s[0][3]));
  float m02 = fmaxf(fmaxf(s[0][4], s[0][5]), fmaxf(s[0][6], s[0][7]));
  float m03 = fmaxf(fmaxf(s[0][8], s[0][9]), fmaxf(s[0][10], s[0][11]));
  float m04 = fmaxf(fmaxf(s[0][12], s[0][13]), fmaxf(s[0][14], s[0][15]));
  float m11 = fmaxf(fmaxf(s[1][0], s[1][1]), fmaxf(s[1][2], s[1][3]));
  float m12 = fmaxf(fmaxf(s[1][4], s[1][5]), fmaxf(s[1][6], s[1][7]));
  float m13 = fmaxf(fmaxf(s[1][8], s[1][9]), fmaxf(s[1][10], s[1][11]));
  float m14 = fmaxf(fmaxf(s[1][12], s[1][13]), fmaxf(s[1][14], s[1][15]));
  float ml = fmaxf(fmaxf(fmaxf(m01,m02), fmaxf(m03,m04)),
                   fmaxf(fmaxf(m11,m12), fmaxf(m13,m14)));
  if (!__all(ml <= mrun + 7.0f)) {
    float m2 = fmaxf(ml, __shfl_xor(ml, 32, 64));
    float mn = fmaxf(mrun, m2);
    float sc = __builtin_amdgcn_exp2f(mrun - mn);
    lrun *= sc;
    mrun = mn;
    #pragma unroll
    for (int dd=0; dd<2; ++dd)
      #pragma unroll
      for (int r=0;r<16;++r) o[dd][r] *= sc;
  }
  float m0 = mrun;
  float a0=0.f, a1=0.f, a2=0.f, a3=0.f;
  #pragma unroll
  for (int st=0; st<2; ++st)
    #pragma unroll
    for (int r=0;r<16;r+=4) {
      float p0 = __builtin_amdgcn_exp2f(s[st][r+0] - m0); s[st][r+0] = p0; a0 += p0;
      float p1 = __builtin_amdgcn_exp2f(s[st][r+1] - m0); s[st][r+1] = p1; a1 += p1;
      float p2 = __builtin_amdgcn_exp2f(s[st][r+2] - m0); s[st][r+2] = p2; a2 += p2;
      float p3 = __builtin_amdgcn_exp2f(s[st][r+3] - m0); s[st][r+3] = p3; a3 += p3;
    }
  lrun += (a0 + a1) + (a2 + a3);
  #pragma unroll
  for (int st=0; st<2; ++st)
    #pragma unroll
    for (int s_t=0; s_t<2; ++s_t) {
      unsigned int c0 = pk_u32(s[st][8*s_t+0], s[st][8*s_t+1]);
      unsigned int c1 = pk_u32(s[st][8*s_t+2], s[st][8*s_t+3]);
      unsigned int d0 = pk_u32(s[st][8*s_t+4], s[st][8*s_t+5]);
      unsigned int d1 = pk_u32(s[st][8*s_t+6], s[st][8*s_t+7]);
      asm("v_permlane32_swap_b32 %0, %1" : "+v"(c0), "+v"(d0));
      asm("v_permlane32_swap_b32 %0, %1" : "+v"(c1), "+v"(d1));
      union { unsigned int u[4]; f16x8 v; } pkk;
      pkk.u[0] = c0; pkk.u[1] = c1; pkk.u[2] = d0; pkk.u[3] = d1;
      pf[st*2 + s_t] = pkk.v;
    }
}

// ---------------- W f32 -> f16 conversion (4 planes of 1024x1024) ----------
__global__ __launch_bounds__(256) void wconv_k(
    const float* __restrict__ Wq, const float* __restrict__ Wk,
    const float* __restrict__ Wv, const float* __restrict__ Wo,
    unsigned short* __restrict__ WF)
{
  const int plane = blockIdx.y;
  const float* __restrict__ s = (plane==0)? Wq : (plane==1)? Wk : (plane==2)? Wv : Wo;
  size_t off = ((size_t)blockIdx.x*256 + threadIdx.x) * 8;
  float4 f0 = *(const float4*)(s + off);
  float4 f1 = *(const float4*)(s + off + 4);
  *(ushort8*)&WF[(size_t)plane*1048576 + off] = pack8_rtz(f0, f1);
}

// ---------------- fused QKV projection GEMM: 1-barrier dbuf prefetch -------
// z=0: Q -> f16 plane (scaled by log2e); z=1: K; z=2: V -> per-head transposed
// B (f16 plane): gload16 into the idle buffer at iter start (full compute
// phase to land). A (f32): 2-deep reg prefetch -> the pack+ds_write before
// the barrier uses regs that landed a full iteration ago.
__global__ __launch_bounds__(256) void qkv_k(
    const float* __restrict__ Aq, const float* __restrict__ Ak, const float* __restrict__ Av,
    const unsigned short* __restrict__ WF,
    const float* __restrict__ bq, const float* __restrict__ bk, const float* __restrict__ bv,
    unsigned short* __restrict__ Qf, unsigned short* __restrict__ Kf, unsigned short* __restrict__ Vt)
{
  const int z = blockIdx.z;
  const float* __restrict__ A    = (z==0)? Aq : (z==1)? Ak : Av;
  const unsigned short* __restrict__ W = WF + (size_t)z*1048576;
  const float* __restrict__ bias = (z==0)? bq : (z==1)? bk : bv;

  __shared__ unsigned short Ah[2][128*32];
  __shared__ unsigned short Bh[2][128*32];

  const int tid  = threadIdx.x;
  const int lane = tid & 63;
  const int w    = tid >> 6;
  const int wm   = w >> 1, wn = w & 1;
  const int row0 = blockIdx.x * 128;
  const int col0 = blockIdx.y * 128;

  // A staging geometry (2 chunks of 8 f32 per thread)
  const float* aptr[2]; int alidx[2];
  #pragma unroll
  for (int i=0;i<2;++i) {
    int c = tid + i*256;
    int r = c >> 2, slot = c & 3;
    alidx[i] = r*32 + ((slot ^ ((r>>1)&3))*8);
    aptr[i]  = A + (size_t)(row0 + r)*1024 + slot*8;
  }

  f32x4 acc[4][4] = {};

  // prologue: stage tile 0 (A manual, B gload); load A tile 1 to regs
  #pragma unroll
  for (int j=0;j<2;++j) {
    int r  = w*32 + j*16 + (lane>>2);
    int sl = (lane & 3) ^ ((r>>1)&3);
    gload16(W + (size_t)(col0 + r)*1024 + sl*8, &Bh[0][(w*32 + j*16)*32]);
  }
  #pragma unroll
  for (int i=0;i<2;++i) {
    float4 f0 = *(const float4*)(aptr[i]);
    float4 f1 = *(const float4*)(aptr[i] + 4);
    *(ushort8*)&Ah[0][alidx[i]] = pack8_rtz(f0, f1);
  }
  float4 ra[2][2];
  #pragma unroll
  for (int i=0;i<2;++i) {
    ra[i][0] = *(const float4*)(aptr[i] + 32);
    ra[i][1] = *(const float4*)(aptr[i] + 36);
  }
  __syncthreads();

  for (int kk = 0; kk < 32; ++kk) {
    const int cur = kk & 1;
    // issue B(kk+1) gload into the idle buffer
    if (kk < 31) {
      #pragma unroll
      for (int j=0;j<2;++j) {
        int r  = w*32 + j*16 + (lane>>2);
        int sl = (lane & 3) ^ ((r>>1)&3);
        gload16(W + (size_t)(col0 + r)*1024 + (kk+1)*32 + sl*8,
                &Bh[cur^1][(w*32 + j*16)*32]);
      }
    }
    // issue A(kk+2) f32 loads (2 iterations to land)
    float4 na[2][2];
    if (kk < 30) {
      #pragma unroll
      for (int i=0;i<2;++i) {
        na[i][0] = *(const float4*)(aptr[i] + (kk+2)*32);
        na[i][1] = *(const float4*)(aptr[i] + (kk+2)*32 + 4);
      }
    }

    // compute from buffer cur
    f16x8 a_[4], b_[4];
    const int slotR = lane >> 4;
    #pragma unroll
    for (int m=0;m<4;++m) {
      int r = wm*64 + m*16 + (lane & 15);
      a_[m] = *(const f16x8*)&Ah[cur][r*32 + ((slotR ^ ((r>>1)&3))*8)];
    }
    #pragma unroll
    for (int nn=0;nn<4;++nn) {
      int r = wn*64 + nn*16 + (lane & 15);
      b_[nn] = *(const f16x8*)&Bh[cur][r*32 + ((slotR ^ ((r>>1)&3))*8)];
    }
    __builtin_amdgcn_s_setprio(1);
    #pragma unroll
    for (int m=0;m<4;++m)
      #pragma unroll
      for (int nn=0;nn<4;++nn)
        acc[m][nn] = __builtin_amdgcn_mfma_f32_16x16x32_f16(a_[m], b_[nn], acc[m][nn],0,0,0);
    __builtin_amdgcn_s_setprio(0);

    // pack A(kk+1) (regs landed a full iteration ago) -> idle buffer
    if (kk < 31) {
      #pragma unroll
      for (int i=0;i<2;++i)
        *(ushort8*)&Ah[cur^1][alidx[i]] = pack8_rtz(ra[i][0], ra[i][1]);
    }
    __syncthreads();
    #pragma unroll
    for (int i=0;i<2;++i) { ra[i][0] = na[i][0]; ra[i][1] = na[i][1]; }
  }

  // epilogue (C frag: col=lane&15, row=(lane>>4)*4+r)
  #pragma unroll
  for (int m=0;m<4;++m) {
    #pragma unroll
    for (int nn=0;nn<4;++nn) {
      int gcol = col0 + wn*64 + nn*16 + (lane & 15);
      float bsv = bias[gcol];
      if (z == 2) {
        int rbase = row0 + wm*64 + m*16 + (lane>>4)*4;
        int nIdx = rbase >> 11, s0 = rbase & 2047;
        ushort4_t pk;
        #pragma unroll
        for (int r2=0;r2<4;++r2) pk[r2] = f32_to_f16u(acc[m][nn][r2] + bsv);
        *(ushort4_t*)&Vt[((size_t)(nIdx*1024 + gcol))*2048 + s0] = pk;
      } else {
        unsigned short* __restrict__ dst = (z==0)? Qf : Kf;
        const float qsc = (z==0)? LOG2E : 1.0f;   // fold log2(e) into Q
        #pragma unroll
        for (int r2=0;r2<4;++r2) {
          int grow = row0 + wm*64 + m*16 + (lane>>4)*4 + r2;
          dst[(size_t)grow*1024 + gcol] = f32_to_f16u((acc[m][nn][r2] + bsv) * qsc);
        }
      }
    }
  }
}

// ---------------- output projection: 1-barrier dbuf, both operands gload ---
__global__ __launch_bounds__(256) void oproj_k(
    const unsigned short* __restrict__ AO, const unsigned short* __restrict__ W,
    const float* __restrict__ bias, float* __restrict__ out)
{
  __shared__ unsigned short Ah[2][128*32];
  __shared__ unsigned short Bh[2][128*32];

  const int tid  = threadIdx.x;
  const int lane = tid & 63;
  const int w    = tid >> 6;
  const int wm   = w >> 1, wn = w & 1;
  const int row0 = blockIdx.x * 128;
  const int col0 = blockIdx.y * 128;

  f32x4 acc[4][4] = {};

  // prologue: gload tile 0 into buffer 0
  #pragma unroll
  for (int j=0;j<2;++j) {
    int r  = w*32 + j*16 + (lane>>2);
    int sl = (lane & 3) ^ ((r>>1)&3);
    gload16(AO + (size_t)(row0 + r)*1024 + sl*8, &Ah[0][(w*32 + j*16)*32]);
    gload16(W  + (size_t)(col0 + r)*1024 + sl*8, &Bh[0][(w*32 + j*16)*32]);
  }
  __syncthreads();

  for (int kk = 0; kk < 32; ++kk) {
    const int cur = kk & 1;
    if (kk < 31) {
      #pragma unroll
      for (int j=0;j<2;++j) {
        int r  = w*32 + j*16 + (lane>>2);
        int sl = (lane & 3) ^ ((r>>1)&3);
        gload16(AO + (size_t)(row0 + r)*1024 + (kk+1)*32 + sl*8, &Ah[cur^1][(w*32 + j*16)*32]);
        gload16(W  + (size_t)(col0 + r)*1024 + (kk+1)*32 + sl*8, &Bh[cur^1][(w*32 + j*16)*32]);
      }
    }

    f16x8 a_[4], b_[4];
    const int slotR = lane >> 4;
    #pragma unroll
    for (int m=0;m<4;++m) {
      int r = wm*64 + m*16 + (lane & 15);
      a_[m] = *(const f16x8*)&Ah[cur][r*32 + ((slotR ^ ((r>>1)&3))*8)];
    }
    #pragma unroll
    for (int nn=0;nn<4;++nn) {
      int r = wn*64 + nn*16 + (lane & 15);
      b_[nn] = *(const f16x8*)&Bh[cur][r*32 + ((slotR ^ ((r>>1)&3))*8)];
    }
    __builtin_amdgcn_s_setprio(1);
    #pragma unroll
    for (int m=0;m<4;++m)
      #pragma unroll
      for (int nn=0;nn<4;++nn)
        acc[m][nn] = __builtin_amdgcn_mfma_f32_16x16x32_f16(a_[m], b_[nn], acc[m][nn],0,0,0);
    __builtin_amdgcn_s_setprio(0);
    __syncthreads();
  }

  #pragma unroll
  for (int m=0;m<4;++m)
    #pragma unroll
    for (int nn=0;nn<4;++nn) {
      int gcol = col0 + wn*64 + nn*16 + (lane & 15);
      float bsv = bias[gcol];
      #pragma unroll
      for (int r2=0;r2<4;++r2) {
        int grow = row0 + wm*64 + m*16 + (lane>>4)*4 + r2;
        out[(size_t)grow*1024 + gcol] = acc[m][nn][r2] + bsv;
      }
    }
}

// ---------------- Flash attention: 8-wave, 32x32, 2-deep prefetch (r18) ----
__global__ __launch_bounds__(512) void attn_k(
  const unsigned short* __restrict__ Qf, const unsigned short* __restrict__ Kf,
  const unsigned short* __restrict__ Vt, unsigned short* __restrict__ AO)
{
  __shared__ unsigned short Ks[2][64*64];   // K tile (swizzled)   16 KB
  __shared__ unsigned short Vs[2][64*64];   // V^T tile (swizzled) 16 KB

  const int tid = threadIdx.x, lane = tid & 63, w = tid >> 6;
  const int q = lane & 31, h = lane >> 5;

  // T1 XCD swizzle (bijective: 512 % 8 == 0): 64 blocks/XCD = 8 heads' K/V
  const int bid = blockIdx.x;
  const int swz = (bid & 7) * 64 + (bid >> 3);
  const int qt = swz & 7, nh = swz >> 3;
  const int n = nh >> 4, hh = nh & 15;

  // Q fragments (pre-scaled by log2e): qf[t] = Q[qrow][d = 16t + 8h + j]
  f16x8 qf[4];
  {
    int qrow = n*SEQ + qt*256 + w*32 + q;
    #pragma unroll
    for (int t=0;t<4;++t)
      qf[t] = *(const f16x8*)&Qf[(size_t)qrow*1024 + hh*64 + t*16 + h*8];
  }

  f32x16 o[2] = {};          // o[do][r] = O[d = do*32+(r&3)+8*(r>>2)+4h][q]
  float mrun = -1e30f, lrun = 0.f;   // lrun lane-partial (pair-reduced at end)

  const size_t kbase = (size_t)(n*SEQ)*1024 + hh*64;   // K plane [s][1024]
  const size_t vbase = ((size_t)(n*1024 + hh*64))*SEQ; // Vt [d][s]

  // staging geometry: 512 threads cover a full 64x64 tile with ONE 16B
  // chunk each (row = tid>>3, slot = tid&7, 8-slot XOR swizzle)
  const int sr = tid >> 3, ssl = tid & 7;
  const int slidx = sr*64 + ((ssl^(sr&7))*8);

  // incremental source pointers (advance: K by 64 rows = 65536 elems;
  // V by 64 columns)
  const unsigned short* kp = Kf + kbase + (size_t)sr*1024 + ssl*8;
  const unsigned short* vp = Vt + vbase + (size_t)sr*SEQ  + ssl*8;

  // prologue: stage tile 0 directly; load tile 1 into regs
  *(ushort8*)&Ks[0][slidx] = *(const ushort8*)kp;
  *(ushort8*)&Vs[0][slidx] = *(const ushort8*)vp;
  ushort8 kregA = *(const ushort8*)(kp + 65536);
  ushort8 vregA = *(const ushort8*)(vp + 64);
  kp += 2*65536; vp += 128;
  __syncthreads();

  int cur = 0;
  for (int kt = 0; kt < 32; ++kt) {
    // ---- issue loads for tile kt+2 (2 iterations to land) ----
    ushort8 kregB, vregB;
    if (kt + 2 < 32) {
      kregB = *(const ushort8*)kp;
      vregB = *(const ushort8*)vp;
      kp += 65536; vp += 64;
    }

    // ---- S^T = K * Q^T : two 32x32 tiles (st), contraction d via 4 MFMAs --
    f32x16 s[2] = {};
    __builtin_amdgcn_s_setprio(1);
    #pragma unroll
    for (int t=0; t<4; ++t) {
      int gr = ((2*t+h) ^ (q&7))*8;             // row&7 == q&7 for both st
      f16x8 k0 = *(const f16x8*)&Ks[cur][(q     )*64 + gr];
      f16x8 k1 = *(const f16x8*)&Ks[cur][(32 + q)*64 + gr];
      s[0] = __builtin_amdgcn_mfma_f32_32x32x16_f16(k0, qf[t], s[0],0,0,0);
      s[1] = __builtin_amdgcn_mfma_f32_32x32x16_f16(k1, qf[t], s[1],0,0,0);
    }
    __builtin_amdgcn_s_setprio(0);

    // ---- softmax (defer-max, tree rsl) -> P fragments in registers ----
    f16x8 pf[4];
    softmax32(s, o, mrun, lrun, pf);

    // ---- O^T += V^T * P : A = V^T frag (LDS), B = pf (registers) ----
    __builtin_amdgcn_s_setprio(1);
    #pragma unroll
    for (int sg=0; sg<4; ++sg) {
      int gr = ((2*sg+h) ^ (q&7))*8;            // row&7 == q&7 for both do
      f16x8 v0 = *(const f16x8*)&Vs[cur][(q     )*64 + gr];
      f16x8 v1 = *(const f16x8*)&Vs[cur][(32 + q)*64 + gr];
      o[0] = __builtin_amdgcn_mfma_f32_32x32x16_f16(v0, pf[sg], o[0],0,0,0);
      o[1] = __builtin_amdgcn_mfma_f32_32x32x16_f16(v1, pf[sg], o[1],0,0,0);
    }
    __builtin_amdgcn_s_setprio(0);

    // ---- ds_write tile kt+1 (regs landed an iteration ago) -> buf cur^1 ----
    if (kt + 1 < 32) {
      *(ushort8*)&Ks[cur^1][slidx] = kregA;
      *(ushort8*)&Vs[cur^1][slidx] = vregA;
    }
    __syncthreads();
    kregA = kregB; vregA = vregB;     // register rename, free
    cur ^= 1;
  }

  // epilogue: pair lsum reduce (lane ^ 32), packed 8B stores
  float rs = lrun + __shfl_xor(lrun, 32, 64);
  float inv = 1.0f / rs;
  int qrow = n*SEQ + qt*256 + w*32 + q;
  #pragma unroll
  for (int dd=0; dd<2; ++dd)
    #pragma unroll
    for (int rq=0; rq<4; ++rq) {
      union { fp16x2_t h2[2]; ushort4_t u4; } pk4;
      pk4.h2[0] = __builtin_amdgcn_cvt_pkrtz(o[dd][4*rq+0]*inv, o[dd][4*rq+1]*inv);
      pk4.h2[1] = __builtin_amdgcn_cvt_pkrtz(o[dd][4*rq+2]*inv, o[dd][4*rq+3]*inv);
      int d0 = dd*32 + 8*rq + 4*h;
      *(ushort4_t*)&AO[(size_t)qrow*1024 + hh*64 + d0] = pk4.u4;
    }
}

extern "C" void kernel_launch(void* const* d_in, const int* in_sizes, int n_in,
                              void* d_out, int out_size, void* d_ws, size_t ws_size,
                              hipStream_t stream)
{
  (void)in_sizes; (void)n_in; (void)out_size; (void)ws_size;
  const float* query = (const float*)d_in[0];
  const float* key   = (const float*)d_in[1];
  const float* value = (const float*)d_in[2];
  const float* Wq = (const float*)d_in[3];
  const float* bq = (const float*)d_in[4];
  const float* Wk = (const float*)d_in[5];
  const float* bk = (const float*)d_in[6];
  const float* Wv = (const float*)d_in[7];
  const float* bv = (const float*)d_in[8];
  const float* Wo = (const float*)d_in[9];
  const float* bo = (const float*)d_in[10];
  float* out = (float*)d_out;

  unsigned short* ws = (unsigned short*)d_ws;
  const size_t PLANE = (size_t)MROWS * 1024;
  unsigned short* Qf = ws;
  unsigned short* Kf = Qf + PLANE;
  unsigned short* Vt = Kf + PLANE;   // [ (n*16+h)*64+d ][ s ]
  unsigned short* AO = Vt + PLANE;
  unsigned short* WF = AO + PLANE;   // 4 x 1024x1024 f16 weight planes

  dim3 bb(256);
  wconv_k<<<dim3(512,4),  bb, 0, stream>>>(Wq, Wk, Wv, Wo, WF);
  qkv_k <<<dim3(64,8,3),  bb, 0, stream>>>(query, key, value, WF, bq, bk, bv, Qf, Kf, Vt);
  attn_k<<<dim3(512), dim3(512), 0, stream>>>(Qf, Kf, Vt, AO);
  oproj_k<<<dim3(64,8),   bb, 0, stream>>>(AO, WF + 3*1048576, bo, out);
}

// Round 20
// 204.526 us; speedup vs baseline: 1.1013x; 1.1013x over previous
//
#include <hip/hip_runtime.h>
#include <stdint.h>

#define SEQ 2048
#define MROWS 8192
#define LOG2E 1.44269504f

typedef __attribute__((ext_vector_type(8))) _Float16 f16x8;
typedef __attribute__((ext_vector_type(2))) __fp16 fp16x2_t;   // cvt_pkrtz return type
typedef __attribute__((ext_vector_type(8))) unsigned short ushort8;
typedef __attribute__((ext_vector_type(4))) unsigned short ushort4_t;
typedef __attribute__((ext_vector_type(4))) float f32x4;
typedef __attribute__((ext_vector_type(16))) float f32x16;

__device__ __forceinline__ unsigned short f32_to_f16u(float f) {
  union { _Float16 h; unsigned short u; } v; v.h = (_Float16)f; return v.u;
}

__device__ __forceinline__ unsigned int pk_u32(float a, float b) {
  union { fp16x2_t h; unsigned int u; } v;
  v.h = __builtin_amdgcn_cvt_pkrtz(a, b);
  return v.u;
}

__device__ __forceinline__ ushort8 pack8_rtz(float4 f0, float4 f1) {
  union { fp16x2_t h2[4]; ushort8 u8; } pk;
  pk.h2[0] = __builtin_amdgcn_cvt_pkrtz(f0.x, f0.y);
  pk.h2[1] = __builtin_amdgcn_cvt_pkrtz(f0.z, f0.w);
  pk.h2[2] = __builtin_amdgcn_cvt_pkrtz(f1.x, f1.y);
  pk.h2[3] = __builtin_amdgcn_cvt_pkrtz(f1.z, f1.w);
  return pk.u8;
}

// async global(16B/lane) -> LDS (wave-uniform base + lane*16)
__device__ __forceinline__ void gload16(const void* g, void* l) {
  __builtin_amdgcn_global_load_lds(
      (const __attribute__((address_space(1))) unsigned int*)g,
      (__attribute__((address_space(3))) unsigned int*)l, 16, 0, 0);
}

// softmax: max-tree vote defer-max, tree-summed rsl; exp2 overwrites s with P;
// pack P for the 32x32 PV B-operand via cvt_pk + permlane32_swap.
__device__ __forceinline__ void softmax32(f32x16* s, f32x16* o,
                                          float& mrun, float& lrun, f16x8* pf) {
  float m01 = fmaxf(fmaxf(s[0][0], s[0][1]), fmaxf(s[0][2], s[0][3]));
  float m02 = fmaxf(fmaxf(s[0][4], s[0][5]), fmaxf(s[0][6], s[0][7]));
  float m03 = fmaxf(fmaxf(s[0][8], s[0][9]), fmaxf(s[0][10], s[0][11]));
  float m04 = fmaxf(fmaxf(s[0][12], s[0][13]), fmaxf(s[0][14], s[0][15]));
  float m11 = fmaxf(fmaxf(s[1][0], s[1][1]), fmaxf(s[1][2], s[1][3]));
  float m12 = fmaxf(fmaxf(s[1][4], s[1][5]), fmaxf(s[1][6], s[1][7]));
  float m13 = fmaxf(fmaxf(s[1][8], s[1][9]), fmaxf(s[1][10], s[1][11]));
  float m14 = fmaxf(fmaxf(s[1][12], s[1][13]), fmaxf(s[1][14], s[1][15]));
  float ml = fmaxf(fmaxf(fmaxf(m01,m02), fmaxf(m03,m04)),
                   fmaxf(fmaxf(m11,m12), fmaxf(m13,m14)));
  if (!__all(ml <= mrun + 7.0f)) {
    float m2 = fmaxf(ml, __shfl_xor(ml, 32, 64));
    float mn = fmaxf(mrun, m2);
    float sc = __builtin_amdgcn_exp2f(mrun - mn);
    lrun *= sc;
    mrun = mn;
    #pragma unroll
    for (int dd=0; dd<2; ++dd)
      #pragma unroll
      for (int r=0;r<16;++r) o[dd][r] *= sc;
  }
  float m0 = mrun;
  float a0=0.f, a1=0.f, a2=0.f, a3=0.f;
  #pragma unroll
  for (int st=0; st<2; ++st)
    #pragma unroll
    for (int r=0;r<16;r+=4) {
      float p0 = __builtin_amdgcn_exp2f(s[st][r+0] - m0); s[st][r+0] = p0; a0 += p0;
      float p1 = __builtin_amdgcn_exp2f(s[st][r+1] - m0); s[st][r+1] = p1; a1 += p1;
      float p2 = __builtin_amdgcn_exp2f(s[st][r+2] - m0); s[st][r+2] = p2; a2 += p2;
      float p3 = __builtin_amdgcn_exp2f(s[st][r+3] - m0); s[st][r+3] = p3; a3 += p3;
    }
  lrun += (a0 + a1) + (a2 + a3);
  #pragma unroll
  for (int st=0; st<2; ++st)
    #pragma unroll
    for (int s_t=0; s_t<2; ++s_t) {
      unsigned int c0 = pk_u32(s[st][8*s_t+0], s[st][8*s_t+1]);
      unsigned int c1 = pk_u32(s[st][8*s_t+2], s[st][8*s_t+3]);
      unsigned int d0 = pk_u32(s[st][8*s_t+4], s[st][8*s_t+5]);
      unsigned int d1 = pk_u32(s[st][8*s_t+6], s[st][8*s_t+7]);
      asm("v_permlane32_swap_b32 %0, %1" : "+v"(c0), "+v"(d0));
      asm("v_permlane32_swap_b32 %0, %1" : "+v"(c1), "+v"(d1));
      union { unsigned int u[4]; f16x8 v; } pkk;
      pkk.u[0] = c0; pkk.u[1] = c1; pkk.u[2] = d0; pkk.u[3] = d1;
      pf[st*2 + s_t] = pkk.v;
    }
}

// ---------------- W f32 -> f16 conversion (4 planes of 1024x1024) ----------
__global__ __launch_bounds__(256) void wconv_k(
    const float* __restrict__ Wq, const float* __restrict__ Wk,
    const float* __restrict__ Wv, const float* __restrict__ Wo,
    unsigned short* __restrict__ WF)
{
  const int plane = blockIdx.y;
  const float* __restrict__ s = (plane==0)? Wq : (plane==1)? Wk : (plane==2)? Wv : Wo;
  size_t off = ((size_t)blockIdx.x*256 + threadIdx.x) * 8;
  float4 f0 = *(const float4*)(s + off);
  float4 f1 = *(const float4*)(s + off + 4);
  *(ushort8*)&WF[(size_t)plane*1048576 + off] = pack8_rtz(f0, f1);
}

// ---------------- fused QKV projection GEMM (r16 structure + A-load hoist) -
// z=0: Q -> f16 plane (scaled by log2e); z=1: K; z=2: V -> per-head transposed
// Single-buffer 16KB LDS, 2 barriers/iter. A(k+1)'s f32 loads are issued at
// the top of compute(k) so the staging window holds only pack + ds_write.
// B (f16 plane) via global_load_lds.
__global__ __launch_bounds__(256) void qkv_k(
    const float* __restrict__ Aq, const float* __restrict__ Ak, const float* __restrict__ Av,
    const unsigned short* __restrict__ WF,
    const float* __restrict__ bq, const float* __restrict__ bk, const float* __restrict__ bv,
    unsigned short* __restrict__ Qf, unsigned short* __restrict__ Kf, unsigned short* __restrict__ Vt)
{
  const int z = blockIdx.z;
  const float* __restrict__ A    = (z==0)? Aq : (z==1)? Ak : Av;
  const unsigned short* __restrict__ W = WF + (size_t)z*1048576;
  const float* __restrict__ bias = (z==0)? bq : (z==1)? bk : bv;

  __shared__ unsigned short Ah[128*32];
  __shared__ unsigned short Bh[128*32];

  const int tid  = threadIdx.x;
  const int lane = tid & 63;
  const int w    = tid >> 6;
  const int wm   = w >> 1, wn = w & 1;
  const int row0 = blockIdx.x * 128;
  const int col0 = blockIdx.y * 128;

  // A staging geometry (2 chunks of 8 f32 per thread)
  const float* aptr[2]; int alidx[2];
  #pragma unroll
  for (int i=0;i<2;++i) {
    int c = tid + i*256;
    int r = c >> 2, slot = c & 3;
    alidx[i] = r*32 + ((slot ^ ((r>>1)&3))*8);
    aptr[i]  = A + (size_t)(row0 + r)*1024 + slot*8;
  }

  f32x4 acc[4][4] = {};

  // prologue: load A tile 0 into regs
  float4 ra[2][2];
  #pragma unroll
  for (int i=0;i<2;++i) {
    ra[i][0] = *(const float4*)(aptr[i]);
    ra[i][1] = *(const float4*)(aptr[i] + 4);
  }

  for (int kk = 0; kk < 32; ++kk) {
    __syncthreads();   // previous compute's LDS reads complete
    // staging window: B gload issue + A pack/ds_write only (loads pre-landed)
    #pragma unroll
    for (int j=0;j<2;++j) {
      int r  = w*32 + j*16 + (lane>>2);
      int sl = (lane & 3) ^ ((r>>1)&3);
      gload16(W + (size_t)(col0 + r)*1024 + kk*32 + sl*8, &Bh[(w*32 + j*16)*32]);
    }
    #pragma unroll
    for (int i=0;i<2;++i)
      *(ushort8*)&Ah[alidx[i]] = pack8_rtz(ra[i][0], ra[i][1]);
    __syncthreads();   // drains B gload + A ds_writes

    // issue A(kk+1) loads immediately -- they land during compute
    if (kk < 31) {
      #pragma unroll
      for (int i=0;i<2;++i) {
        ra[i][0] = *(const float4*)(aptr[i] + (kk+1)*32);
        ra[i][1] = *(const float4*)(aptr[i] + (kk+1)*32 + 4);
      }
    }

    f16x8 a_[4], b_[4];
    const int slotR = lane >> 4;
    #pragma unroll
    for (int m=0;m<4;++m) {
      int r = wm*64 + m*16 + (lane & 15);
      a_[m] = *(const f16x8*)&Ah[r*32 + ((slotR ^ ((r>>1)&3))*8)];
    }
    #pragma unroll
    for (int nn=0;nn<4;++nn) {
      int r = wn*64 + nn*16 + (lane & 15);
      b_[nn] = *(const f16x8*)&Bh[r*32 + ((slotR ^ ((r>>1)&3))*8)];
    }
    __builtin_amdgcn_s_setprio(1);
    #pragma unroll
    for (int m=0;m<4;++m)
      #pragma unroll
      for (int nn=0;nn<4;++nn)
        acc[m][nn] = __builtin_amdgcn_mfma_f32_16x16x32_f16(a_[m], b_[nn], acc[m][nn],0,0,0);
    __builtin_amdgcn_s_setprio(0);
  }

  // epilogue (C frag: col=lane&15, row=(lane>>4)*4+r)
  #pragma unroll
  for (int m=0;m<4;++m) {
    #pragma unroll
    for (int nn=0;nn<4;++nn) {
      int gcol = col0 + wn*64 + nn*16 + (lane & 15);
      float bsv = bias[gcol];
      if (z == 2) {
        int rbase = row0 + wm*64 + m*16 + (lane>>4)*4;
        int nIdx = rbase >> 11, s0 = rbase & 2047;
        ushort4_t pk;
        #pragma unroll
        for (int r2=0;r2<4;++r2) pk[r2] = f32_to_f16u(acc[m][nn][r2] + bsv);
        *(ushort4_t*)&Vt[((size_t)(nIdx*1024 + gcol))*2048 + s0] = pk;
      } else {
        unsigned short* __restrict__ dst = (z==0)? Qf : Kf;
        const float qsc = (z==0)? LOG2E : 1.0f;   // fold log2(e) into Q
        #pragma unroll
        for (int r2=0;r2<4;++r2) {
          int grow = row0 + wm*64 + m*16 + (lane>>4)*4 + r2;
          dst[(size_t)grow*1024 + gcol] = f32_to_f16u((acc[m][nn][r2] + bsv) * qsc);
        }
      }
    }
  }
}

// ---------------- output projection: out = AO(f16) @ WoF^T + bo (f32) ------
// BOTH operands staged via global_load_lds (r16/r18 form).
__global__ __launch_bounds__(256) void oproj_k(
    const unsigned short* __restrict__ AO, const unsigned short* __restrict__ W,
    const float* __restrict__ bias, float* __restrict__ out)
{
  __shared__ unsigned short Ah[128*32];
  __shared__ unsigned short Bh[128*32];

  const int tid  = threadIdx.x;
  const int lane = tid & 63;
  const int w    = tid >> 6;
  const int wm   = w >> 1, wn = w & 1;
  const int row0 = blockIdx.x * 128;
  const int col0 = blockIdx.y * 128;

  f32x4 acc[4][4] = {};

  for (int k0 = 0; k0 < 1024; k0 += 32) {
    __syncthreads();
    #pragma unroll
    for (int j=0;j<2;++j) {
      int r  = w*32 + j*16 + (lane>>2);
      int sl = (lane & 3) ^ ((r>>1)&3);
      gload16(AO + (size_t)(row0 + r)*1024 + k0 + sl*8, &Ah[(w*32 + j*16)*32]);
      gload16(W  + (size_t)(col0 + r)*1024 + k0 + sl*8, &Bh[(w*32 + j*16)*32]);
    }
    __syncthreads();

    f16x8 a_[4], b_[4];
    const int slotR = lane >> 4;
    #pragma unroll
    for (int m=0;m<4;++m) {
      int r = wm*64 + m*16 + (lane & 15);
      a_[m] = *(const f16x8*)&Ah[r*32 + ((slotR ^ ((r>>1)&3))*8)];
    }
    #pragma unroll
    for (int nn=0;nn<4;++nn) {
      int r = wn*64 + nn*16 + (lane & 15);
      b_[nn] = *(const f16x8*)&Bh[r*32 + ((slotR ^ ((r>>1)&3))*8)];
    }
    #pragma unroll
    for (int m=0;m<4;++m)
      #pragma unroll
      for (int nn=0;nn<4;++nn)
        acc[m][nn] = __builtin_amdgcn_mfma_f32_16x16x32_f16(a_[m], b_[nn], acc[m][nn],0,0,0);
  }

  #pragma unroll
  for (int m=0;m<4;++m)
    #pragma unroll
    for (int nn=0;nn<4;++nn) {
      int gcol = col0 + wn*64 + nn*16 + (lane & 15);
      float bsv = bias[gcol];
      #pragma unroll
      for (int r2=0;r2<4;++r2) {
        int grow = row0 + wm*64 + m*16 + (lane>>4)*4 + r2;
        out[(size_t)grow*1024 + gcol] = acc[m][nn][r2] + bsv;
      }
    }
}

// ---------------- Flash attention: 8-wave, 32x32, 2-deep prefetch (r18) ----
__global__ __launch_bounds__(512) void attn_k(
  const unsigned short* __restrict__ Qf, const unsigned short* __restrict__ Kf,
  const unsigned short* __restrict__ Vt, unsigned short* __restrict__ AO)
{
  __shared__ unsigned short Ks[2][64*64];   // K tile (swizzled)   16 KB
  __shared__ unsigned short Vs[2][64*64];   // V^T tile (swizzled) 16 KB

  const int tid = threadIdx.x, lane = tid & 63, w = tid >> 6;
  const int q = lane & 31, h = lane >> 5;

  // T1 XCD swizzle (bijective: 512 % 8 == 0): 64 blocks/XCD = 8 heads' K/V
  const int bid = blockIdx.x;
  const int swz = (bid & 7) * 64 + (bid >> 3);
  const int qt = swz & 7, nh = swz >> 3;
  const int n = nh >> 4, hh = nh & 15;

  // Q fragments (pre-scaled by log2e): qf[t] = Q[qrow][d = 16t + 8h + j]
  f16x8 qf[4];
  {
    int qrow = n*SEQ + qt*256 + w*32 + q;
    #pragma unroll
    for (int t=0;t<4;++t)
      qf[t] = *(const f16x8*)&Qf[(size_t)qrow*1024 + hh*64 + t*16 + h*8];
  }

  f32x16 o[2] = {};          // o[do][r] = O[d = do*32+(r&3)+8*(r>>2)+4h][q]
  float mrun = -1e30f, lrun = 0.f;   // lrun lane-partial (pair-reduced at end)

  const size_t kbase = (size_t)(n*SEQ)*1024 + hh*64;   // K plane [s][1024]
  const size_t vbase = ((size_t)(n*1024 + hh*64))*SEQ; // Vt [d][s]

  // staging geometry: 512 threads cover a full 64x64 tile with ONE 16B
  // chunk each (row = tid>>3, slot = tid&7, 8-slot XOR swizzle)
  const int sr = tid >> 3, ssl = tid & 7;
  const int slidx = sr*64 + ((ssl^(sr&7))*8);

  // incremental source pointers (advance: K by 64 rows = 65536 elems;
  // V by 64 columns)
  const unsigned short* kp = Kf + kbase + (size_t)sr*1024 + ssl*8;
  const unsigned short* vp = Vt + vbase + (size_t)sr*SEQ  + ssl*8;

  // prologue: stage tile 0 directly; load tile 1 into regs
  *(ushort8*)&Ks[0][slidx] = *(const ushort8*)kp;
  *(ushort8*)&Vs[0][slidx] = *(const ushort8*)vp;
  ushort8 kregA = *(const ushort8*)(kp + 65536);
  ushort8 vregA = *(const ushort8*)(vp + 64);
  kp += 2*65536; vp += 128;
  __syncthreads();

  int cur = 0;
  for (int kt = 0; kt < 32; ++kt) {
    // ---- issue loads for tile kt+2 (2 iterations to land) ----
    ushort8 kregB, vregB;
    if (kt + 2 < 32) {
      kregB = *(const ushort8*)kp;
      vregB = *(const ushort8*)vp;
      kp += 65536; vp += 64;
    }

    // ---- S^T = K * Q^T : two 32x32 tiles (st), contraction d via 4 MFMAs --
    f32x16 s[2] = {};
    __builtin_amdgcn_s_setprio(1);
    #pragma unroll
    for (int t=0; t<4; ++t) {
      int gr = ((2*t+h) ^ (q&7))*8;             // row&7 == q&7 for both st
      f16x8 k0 = *(const f16x8*)&Ks[cur][(q     )*64 + gr];
      f16x8 k1 = *(const f16x8*)&Ks[cur][(32 + q)*64 + gr];
      s[0] = __builtin_amdgcn_mfma_f32_32x32x16_f16(k0, qf[t], s[0],0,0,0);
      s[1] = __builtin_amdgcn_mfma_f32_32x32x16_f16(k1, qf[t], s[1],0,0,0);
    }
    __builtin_amdgcn_s_setprio(0);

    // ---- softmax (defer-max, tree rsl) -> P fragments in registers ----
    f16x8 pf[4];
    softmax32(s, o, mrun, lrun, pf);

    // ---- O^T += V^T * P : A = V^T frag (LDS), B = pf (registers) ----
    __builtin_amdgcn_s_setprio(1);
    #pragma unroll
    for (int sg=0; sg<4; ++sg) {
      int gr = ((2*sg+h) ^ (q&7))*8;            // row&7 == q&7 for both do
      f16x8 v0 = *(const f16x8*)&Vs[cur][(q     )*64 + gr];
      f16x8 v1 = *(const f16x8*)&Vs[cur][(32 + q)*64 + gr];
      o[0] = __builtin_amdgcn_mfma_f32_32x32x16_f16(v0, pf[sg], o[0],0,0,0);
      o[1] = __builtin_amdgcn_mfma_f32_32x32x16_f16(v1, pf[sg], o[1],0,0,0);
    }
    __builtin_amdgcn_s_setprio(0);

    // ---- ds_write tile kt+1 (regs landed an iteration ago) -> buf cur^1 ----
    if (kt + 1 < 32) {
      *(ushort8*)&Ks[cur^1][slidx] = kregA;
      *(ushort8*)&Vs[cur^1][slidx] = vregA;
    }
    __syncthreads();
    kregA = kregB; vregA = vregB;     // register rename, free
    cur ^= 1;
  }

  // epilogue: pair lsum reduce (lane ^ 32), packed 8B stores
  float rs = lrun + __shfl_xor(lrun, 32, 64);
  float inv = 1.0f / rs;
  int qrow = n*SEQ + qt*256 + w*32 + q;
  #pragma unroll
  for (int dd=0; dd<2; ++dd)
    #pragma unroll
    for (int rq=0; rq<4; ++rq) {
      union { fp16x2_t h2[2]; ushort4_t u4; } pk4;
      pk4.h2[0] = __builtin_amdgcn_cvt_pkrtz(o[dd][4*rq+0]*inv, o[dd][4*rq+1]*inv);
      pk4.h2[1] = __builtin_amdgcn_cvt_pkrtz(o[dd][4*rq+2]*inv, o[dd][4*rq+3]*inv);
      int d0 = dd*32 + 8*rq + 4*h;
      *(ushort4_t*)&AO[(size_t)qrow*1024 + hh*64 + d0] = pk4.u4;
    }
}

extern "C" void kernel_launch(void* const* d_in, const int* in_sizes, int n_in,
                              void* d_out, int out_size, void* d_ws, size_t ws_size,
                              hipStream_t stream)
{
  (void)in_sizes; (void)n_in; (void)out_size; (void)ws_size;
  const float* query = (const float*)d_in[0];
  const float* key   = (const float*)d_in[1];
  const float* value = (const float*)d_in[2];
  const float* Wq = (const float*)d_in[3];
  const float* bq = (const float*)d_in[4];
  const float* Wk = (const float*)d_in[5];
  const float* bk = (const float*)d_in[6];
  const float* Wv = (const float*)d_in[7];
  const float* bv = (const float*)d_in[8];
  const float* Wo = (const float*)d_in[9];
  const float* bo = (const float*)d_in[10];
  float* out = (float*)d_out;

  unsigned short* ws = (unsigned short*)d_ws;
  const size_t PLANE = (size_t)MROWS * 1024;
  unsigned short* Qf = ws;
  unsigned short* Kf = Qf + PLANE;
  unsigned short* Vt = Kf + PLANE;   // [ (n*16+h)*64+d ][ s ]
  unsigned short* AO = Vt + PLANE;
  unsigned short* WF = AO + PLANE;   // 4 x 1024x1024 f16 weight planes

  dim3 bb(256);
  wconv_k<<<dim3(512,4),  bb, 0, stream>>>(Wq, Wk, Wv, Wo, WF);
  qkv_k <<<dim3(64,8,3),  bb, 0, stream>>>(query, key, value, WF, bq, bk, bv, Qf, Kf, Vt);
  attn_k<<<dim3(512), dim3(512), 0, stream>>>(Qf, Kf, Vt, AO);
  oproj_k<<<dim3(64,8),   bb, 0, stream>>>(AO, WF + 3*1048576, bo, out);
}